// Round 10
// baseline (449.936 us; speedup 1.0000x reference)
//
#include <hip/hip_runtime.h>
#include <stdint.h>

// ClassicalHopfield N=8192, P=64.  act_i·N = x_i·m - 64·s_i, m = X^T s (running).
// U_j = 2·(y_j·m) - (s_j<0) - 128, flip ⟺ U_j < 0 (exact tie-break). Flip i:
// ΔU_j = 8·popc(sig_i^sig_j) - 256; m_p += 4·popc(flips & sigT_p) - 2·nf.
// All small integers => exact => bit-identical to the reference.
//
// Round-10: TWO-WAVE PIPELINE. Cross-round ablation (R5..R9 all ~6000cy/blk
// nominal despite 2-3x resolve-op differences; VALUBusy ~32% of one SIMD)
// => single wave is issue+stall floor-limited at low effective clock. Wave w
// owns blocks of parity w. Successor margins = stale matvec (vs m from 2
// blocks ago, computed DURING partner's resolve) + cross-sweep of the just-
// published flips (no prefix test: earlier block => applies to all lanes).
// Critical path/step: barrier -> m-upd + xsweep -> resolve -> publish.
// Handoff: u64 flips slot in LDS + one __syncthreads per block. Both waves
// mirror m exactly (same integer updates from identical published data).

#define NB 128
typedef unsigned long long u64;
typedef unsigned u32;

// ws: m0 f[64] | Ysw f[128*4096] (pre-swizzled, glds-linear: [b][j][(G^(j&7))*4+c])
//     | sig u64[8192] | sigT u64[8192] | sps f[8192]   ~2.16 MB

__device__ __forceinline__ void glds16(const void* g, void* l) {
  __builtin_amdgcn_global_load_lds(
      (const __attribute__((address_space(1))) void*)g,
      (__attribute__((address_space(3))) void*)l, 16, 0, 0);
}

__global__ __launch_bounds__(256) void hop_prep(
    const float* __restrict__ X, const float* __restrict__ state,
    const int* __restrict__ perm, float* __restrict__ m0,
    float* __restrict__ Ysw, u64* __restrict__ sig, u64* __restrict__ sigT,
    float* __restrict__ sps)
{
  const int b = blockIdx.x, t = threadIdx.x;
  const int wv = t >> 6, ln = t & 63;
  __shared__ u64 sigL[64];
  __shared__ float red[4][64];

  float acc = 0.f;
  #pragma unroll
  for (int jj = 0; jj < 16; ++jj) {
    const int j = wv*16 + jj;                 // wave-uniform row
    const int r = perm[b*64 + j];
    const float sr = state[r];
    const float x = X[(size_t)r*64 + ln];     // coalesced 256B row
    Ysw[(size_t)b*4096 + j*64 + ((((ln >> 2) ^ (j & 7)) << 2) | (ln & 3))] = x * sr;
    u64 bb = __ballot(x < 0.f);
    if (sr < 0.f) bb = ~bb;                   // sign of y = x*sr
    if (ln == 0) { sig[b*64 + j] = bb; sigL[j] = bb; }
    acc = fmaf(x, sr, acc);
  }
  red[wv][ln] = acc;
  __syncthreads();

  { // column signatures: bit i of sigT_p = bit p of sig_i
    const u64 gs = sigL[ln];
    #pragma unroll
    for (int jj = 0; jj < 16; ++jj) {
      const int p = wv*16 + jj;
      u64 tb = __ballot((unsigned)((gs >> p) & 1ull));
      if (ln == 0) sigT[b*64 + p] = tb;
    }
  }

  if (t < 64) {
    atomicAdd(&m0[t], (red[0][t] + red[1][t]) + (red[2][t] + red[3][t]));
    sps[b*64 + t] = state[perm[b*64 + t]];
  }
}

__device__ __forceinline__ int corr_term(u32 slo, u32 shi, int i) {
  const u32 a = (u32)__builtin_amdgcn_readlane((int)slo, i);
  const u32 b = (u32)__builtin_amdgcn_readlane((int)shi, i);
  return __popc(slo ^ a) + __popc(shi ^ b);
}

// intra-block resolve: fixed point of the serial recurrence (R9, measured-ok)
__device__ __forceinline__ u64 resolve64(const int U0, const u64 sg, const int lane) {
  const u32 slo = (u32)sg, shi = (u32)(sg >> 32);
  u64 F = __ballot(U0 < 0);
  if (!F) return 0ull;
  int Ub = U0;
  { // full prefix application of F
    int a0 = 0, a1 = 0;
    u64 rem = F;
    while (rem) {
      const int i = (int)__builtin_ctzll(rem); rem &= rem - 1ull;
      const int pc = corr_term(slo, shi, i);
      a0 += (lane > i) ? pc : 0;
      if (rem) {
        const int i2 = (int)__builtin_ctzll(rem); rem &= rem - 1ull;
        const int pc2 = corr_term(slo, shi, i2);
        a1 += (lane > i2) ? pc2 : 0;
      }
    }
    const int cnt = (int)__builtin_amdgcn_mbcnt_hi(
        (u32)(F >> 32), __builtin_amdgcn_mbcnt_lo((u32)F, 0u));
    Ub += ((a0 + a1) << 3) - (cnt << 8);
  }
  bool conv = false;
  for (int it = 0; it < 6; ++it) {
    const u64 Fn = __ballot(Ub < 0);
    if (Fn == F) { conv = true; break; }
    u64 dd = Fn ^ F;
    while (dd) {
      const int i = (int)__builtin_ctzll(dd); dd &= dd - 1ull;
      const int pc8 = (corr_term(slo, shi, i) << 3) - 256;
      const int d = ((Fn >> i) & 1ull) ? pc8 : -pc8;
      Ub += (lane > i) ? d : 0;
    }
    F = Fn;
  }
  if (conv) return F;
  // exact serial fallback (rare)
  u64 flips = 0ull, live = ~0ull;
  int Us = U0;
  u64 mm = __ballot(Us < 0);
  while (mm) {
    const int i = (int)__builtin_ctzll(mm);
    flips |= (1ull << i);
    live = (i < 63) ? ((~0ull) << (i + 1)) : 0ull;
    Us += (corr_term(slo, shi, i) << 3) - 256;
    mm = __ballot(Us < 0) & live;
  }
  return flips;
}

// cross-block sweep: flips fb of the PREVIOUS block apply to every lane
__device__ __forceinline__ int xsweep(const u64 fb, const u64 sigPrev, const u64 sigOwn) {
  const u32 plo = (u32)sigPrev, phi = (u32)(sigPrev >> 32);
  const u32 olo = (u32)sigOwn,  ohi = (u32)(sigOwn >> 32);
  int a0 = 0, a1 = 0;
  u64 rem = fb;
  while (rem) {
    const int i = (int)__builtin_ctzll(rem); rem &= rem - 1ull;
    a0 += __popc(olo ^ (u32)__builtin_amdgcn_readlane((int)plo, i))
        + __popc(ohi ^ (u32)__builtin_amdgcn_readlane((int)phi, i));
    if (rem) {
      const int i2 = (int)__builtin_ctzll(rem); rem &= rem - 1ull;
      a1 += __popc(olo ^ (u32)__builtin_amdgcn_readlane((int)plo, i2))
          + __popc(ohi ^ (u32)__builtin_amdgcn_readlane((int)phi, i2));
    }
  }
  const int nf = (int)__popcll(fb);
  return ((a0 + a1) << 3) - (nf << 8);
}

__device__ __forceinline__ int matvec_q(const float* __restrict__ Yl,
                                        const float* __restrict__ mb,
                                        const int ybase, const int lswz) {
  float q0=0.f,q1=0.f,q2=0.f,q3=0.f;
  const float4* mv4 = (const float4*)mb;
  #pragma unroll
  for (int g = 0; g < 16; ++g) {
    const float4 yv = *(const float4*)&Yl[ybase + ((g ^ lswz) << 2)];
    const float4 mv = mv4[g];
    q0 = fmaf(yv.x, mv.x, q0); q1 = fmaf(yv.y, mv.y, q1);
    q2 = fmaf(yv.z, mv.z, q2); q3 = fmaf(yv.w, mv.w, q3);
  }
  return (int)((q0+q1)+(q2+q3));
}

__device__ __forceinline__ void stageTo(float* __restrict__ buf,
                                        const float* __restrict__ ys) {
  #pragma unroll
  for (int it = 0; it < 16; ++it) glds16(ys + it*256, buf + it*256);
}

__global__ __launch_bounds__(128) void hop_solve(
    const int* __restrict__ perm, const float* __restrict__ m0,
    const float* __restrict__ Ysw, const u64* __restrict__ sig,
    const u64* __restrict__ sigT, const float* __restrict__ sps,
    float* __restrict__ out)
{
  __shared__ __align__(16) float Ybuf[2][4096];   // one tile per wave
  __shared__ float mlds[2][64];
  __shared__ u64 fl_lds[4];
  const int tid = threadIdx.x;
  const int wid = tid >> 6, lane = tid & 63;
  const int ybase = lane*64, lswz = lane & 7;

  float mreg = m0[lane];
  mlds[wid][lane] = mreg;

  // prologue: my first tile -> matvec (vs m0); then stage my second tile
  stageTo(Ybuf[wid], Ysw + (size_t)wid*4096 + lane*4);
  u64 sgOwn = sig[wid*64 + lane];        // sig of my next-owned block
  int rOwn  = perm[wid*64 + lane];
  float sOwn = sps[wid*64 + lane];
  u64 sgCur = sig[lane];                 // sig of block 0 (xsweep readlane src)
  u64 stCur = sigT[lane];                // sigT of block 0 (m-update)
  asm volatile("s_waitcnt vmcnt(0)" ::: "memory");
  int U = (matvec_q(Ybuf[wid], mlds[wid], ybase, lswz) << 1)
          - ((sOwn < 0.f) ? 1 : 0) - 128;
  asm volatile("s_waitcnt lgkmcnt(0)" ::: "memory");  // reads done before restage
  stageTo(Ybuf[wid], Ysw + (size_t)(wid+2)*4096 + lane*4);

  for (int b = 0; b < NB; ++b) {
    const bool owner = ((b & 1) == wid);
    if (owner) {
      const u64 flips = resolve64(U, sgOwn, lane);
      out[rOwn] = ((flips >> lane) & 1ull) ? -sOwn : sOwn;
      if (lane == 0) fl_lds[b & 3] = flips;
    }
    __syncthreads();                       // publish flips(b)
    const u64 fb = fl_lds[b & 3];
    { // m-update, both waves (identical integer arithmetic => exact mirror)
      const int nf = (int)__popcll(fb);
      const int pc = (int)__popcll(fb & stCur);
      mreg += (float)(4*pc - 2*nf);
    }
    u64 sgN = 0, stN = 0;
    if (b + 1 < NB) { sgN = sig[(b+1)*64 + lane]; stN = sigT[(b+1)*64 + lane]; }
    if (!owner) {
      // finish margins for my block b+1: stale matvec + flips(b) correction
      if (b + 1 < NB) U += xsweep(fb, sgCur, sgOwn);
    } else {
      // prepare my next block b+2: matvec vs m_b (partner resolves meanwhile)
      if (b + 2 < NB) {
        mlds[wid][lane] = mreg;
        asm volatile("s_waitcnt vmcnt(0)" ::: "memory");   // Y_{b+2} resident
        const int q = matvec_q(Ybuf[wid], mlds[wid], ybase, lswz);
        asm volatile("s_waitcnt lgkmcnt(0)" ::: "memory"); // reads done
        if (b + 4 < NB) stageTo(Ybuf[wid], Ysw + (size_t)(b+4)*4096 + lane*4);
        sgOwn = sig[(b+2)*64 + lane];
        rOwn  = perm[(b+2)*64 + lane];
        sOwn  = sps[(b+2)*64 + lane];
        U = (q << 1) - ((sOwn < 0.f) ? 1 : 0) - 128;
      }
    }
    sgCur = sgN; stCur = stN;
  }
}

extern "C" void kernel_launch(void* const* d_in, const int* in_sizes, int n_in,
                              void* d_out, int out_size, void* d_ws, size_t ws_size,
                              hipStream_t stream) {
  const float* X     = (const float*)d_in[0];
  const float* state = (const float*)d_in[1];
  const int*   perm  = (const int*)d_in[2];
  float* outp = (float*)d_out;

  float* m0  = (float*)d_ws;                 // 64 f
  float* Ysw = m0 + 64;                      // 128*4096 f
  u64*   sig = (u64*)(Ysw + 128*4096);       // 8192 u64
  u64*   sigT= sig + 8192;                   // 8192 u64
  float* sps = (float*)(sigT + 8192);        // 8192 f

  hipMemsetAsync(m0, 0, 64*sizeof(float), stream);
  hop_prep<<<dim3(NB), dim3(256), 0, stream>>>(X, state, perm, m0, Ysw, sig, sigT, sps);
  hop_solve<<<dim3(1), dim3(128), 0, stream>>>(perm, m0, Ysw, sig, sigT, sps, outp);
}